// Round 19
// baseline (267.029 us; speedup 1.0000x reference)
//
#include <hip/hip_runtime.h>
#include <math.h>

#define DIM 1024
#define NHEAD 16
#define HD 64
#define HIDDEN 4096
#define SEQ 1024
#define BATCH 4
#define ROWS (BATCH*SEQ)   // 4096 tokens

typedef __attribute__((ext_vector_type(8))) short bf16x8;
typedef __attribute__((ext_vector_type(4))) float f32x4;
typedef __attribute__((ext_vector_type(4))) unsigned short us4;

__device__ __forceinline__ unsigned short f2bf(float f) {
  unsigned u = __builtin_bit_cast(unsigned, f);
  u += 0x7fffu + ((u >> 16) & 1u);           // round-to-nearest-even
  return (unsigned short)(u >> 16);
}

__device__ __forceinline__ float bf2f(unsigned short h) {
  unsigned u = (unsigned)h << 16;
  return __builtin_bit_cast(float, u);
}

// pack two f32 -> (bf16(b)<<16)|bf16(a), round-half-up (err <= 2^-9 rel): 2 add + 1 perm
__device__ __forceinline__ unsigned pkbf(float a, float b) {
  unsigned ua = __builtin_bit_cast(unsigned, a) + 0x8000u;
  unsigned ub = __builtin_bit_cast(unsigned, b) + 0x8000u;
  return __builtin_amdgcn_perm(ub, ua, 0x07060302u);  // [ub.b3 ub.b2 ua.b3 ua.b2]
}

__device__ __forceinline__ float f3(float a, float b, float c) {  // fuses to v_max3_f32
  return fmaxf(fmaxf(a, b), c);
}

__device__ __forceinline__ void glds16(const void* g, void* l) {
  __builtin_amdgcn_global_load_lds((const __attribute__((address_space(1))) void*)g,
                                   (__attribute__((address_space(3))) void*)l,
                                   16, 0, 0);
}

// ---------------- fp32 -> bf16 weight conversion (all 4 weights, one launch) ----------------
__global__ void cvt_all(const float* __restrict__ a, const float* __restrict__ b,
                        const float* __restrict__ c, const float* __restrict__ d,
                        unsigned short* __restrict__ oa, unsigned short* __restrict__ ob,
                        unsigned short* __restrict__ oc, unsigned short* __restrict__ od) {
  const int na = 3 * DIM * DIM / 4, nb = DIM * DIM / 4, nc = HIDDEN * DIM / 4, nd = DIM * HIDDEN / 4;
  const int total = na + nb + nc + nd;
  for (int i = blockIdx.x * blockDim.x + threadIdx.x; i < total; i += gridDim.x * blockDim.x) {
    const float* in; unsigned short* out; int j = i;
    if (j < na)             { in = a; out = oa; }
    else if ((j -= na) < nb){ in = b; out = ob; }
    else if ((j -= nb) < nc){ in = c; out = oc; }
    else                    { j -= nc; in = d; out = od; }
    float4 v = reinterpret_cast<const float4*>(in)[j];
    us4 o = { f2bf(v.x), f2bf(v.y), f2bf(v.z), f2bf(v.w) };
    reinterpret_cast<us4*>(out)[j] = o;
  }
}

// ---------------- LayerNorm: fp32 or bf16 row -> bf16 normalized ----------------
template<bool IN_BF16>
__global__ void ln_kernel(const void* __restrict__ xv, const float* __restrict__ w,
                          const float* __restrict__ b, unsigned short* __restrict__ out) {
  int row = blockIdx.x;
  int t = threadIdx.x;
  float4 v;
  if (IN_BF16) {
    const unsigned short* xr = (const unsigned short*)xv + (size_t)row * DIM;
    us4 hv = *reinterpret_cast<const us4*>(xr + t * 4);
    v.x = bf2f(hv[0]); v.y = bf2f(hv[1]); v.z = bf2f(hv[2]); v.w = bf2f(hv[3]);
  } else {
    const float* xr = (const float*)xv + (size_t)row * DIM;
    v = *reinterpret_cast<const float4*>(xr + t * 4);
  }
  float s  = v.x + v.y + v.z + v.w;
  float s2 = v.x*v.x + v.y*v.y + v.z*v.z + v.w*v.w;
#pragma unroll
  for (int m = 1; m < 64; m <<= 1) { s += __shfl_xor(s, m); s2 += __shfl_xor(s2, m); }
  __shared__ float red[8];
  int wv = t >> 6, ln = t & 63;
  if (ln == 0) { red[wv] = s; red[4 + wv] = s2; }
  __syncthreads();
  s  = red[0] + red[1] + red[2] + red[3];
  s2 = red[4] + red[5] + red[6] + red[7];
  float mu  = s * (1.0f / DIM);
  float var = s2 * (1.0f / DIM) - mu * mu;
  float rs  = rsqrtf(var + 1e-5f);
  float4 wv4 = *reinterpret_cast<const float4*>(w + t * 4);
  float4 bv4 = *reinterpret_cast<const float4*>(b + t * 4);
  us4 o = { f2bf((v.x - mu) * rs * wv4.x + bv4.x),
            f2bf((v.y - mu) * rs * wv4.y + bv4.y),
            f2bf((v.z - mu) * rs * wv4.z + bv4.z),
            f2bf((v.w - mu) * rs * wv4.w + bv4.w) };
  *reinterpret_cast<us4*>(out + (size_t)row * DIM + t * 4) = o;
}

// ---------------- 128x64 bf16 NT GEMM, BK=64 2-phase dbuf (ALL four GEMMs) ----------------
// T1 XCD swizzle: linear id = bx + 32*by -> XCD = bx%8 scattered the 32 M-blocks of each
// B-panel over all 8 XCDs (panel fetched 8x, staging sources L3/HBM ~900cyc > 1-step
// lookahead). Chunked remap swz=(id%8)*(nwg/8)+id/8 (bijective: all grids %8==0) pins
// whole B-panels to one XCD -> staging becomes L2-hit (~200cyc), covered by lookahead.
// MODE 0: QKV  -> q (bias+scale), k, vT (bf16)
// MODE 1: proj -> xres_bf16 = acc + bias + x_fp32
// MODE 2: mlp1 -> outh = gelu(acc + bias) (bf16, tanh-approx)
// MODE 3: mlp2 -> out_fp32 = acc + bias + xres_bf16
template<int MODE>
__global__ __launch_bounds__(256)
void gemm64k(const unsigned short* __restrict__ A, const unsigned short* __restrict__ Bw,
             int K, int N,
             const float* __restrict__ bias, const void* __restrict__ resid,
             float* __restrict__ outf, unsigned short* __restrict__ outh,
             unsigned short* __restrict__ qo, unsigned short* __restrict__ ko,
             unsigned short* __restrict__ vto,
             const float* __restrict__ qbias, const float* __restrict__ vbias)
{
  __shared__ unsigned short smA[2][128 * 64];   // 16KB each
  __shared__ unsigned short smB[2][64 * 64];    // 8KB each
  const int tid = threadIdx.x;
  const int wv = tid >> 6, ln = tid & 63;

  // T1 chunked XCD swizzle (bijective: nwg % 8 == 0 for all four launches)
  const int nwg = gridDim.x * gridDim.y;
  const int lid = blockIdx.x + gridDim.x * blockIdx.y;
  const int swz = (lid & 7) * (nwg >> 3) + (lid >> 3);
  const int bx = swz & (gridDim.x - 1);         // gridDim.x = 32 (power of 2)
  const int by = swz / gridDim.x;
  const int tile_m = bx * 128, tile_n = by * 64;
  const int wm = (wv >> 1) * 64, wn = (wv & 1) * 32;

  const int srow8 = ln >> 3;                    // row in 8-row group
  const int sch8  = (ln & 7) ^ srow8;           // pre-swizzled global chunk (of 8)
  const unsigned short* gA = A  + (size_t)(tile_m + wv * 8 + srow8) * K + sch8 * 8;
  const unsigned short* gB = Bw + (size_t)(tile_n + wv * 8 + srow8) * K + sch8 * 8;

  f32x4 acc[4][2] = {};
  const int lr = ln & 15, g = ln >> 4;
  const int rx = lr & 7;                        // read-side row XOR key

  auto stage = [&](int buf, int k0) {
#pragma unroll
    for (int p = 0; p < 4; p++)                 // A: 128 rows
      glds16(gA + (size_t)(p * 32) * K + k0, &smA[buf][(p * 32 + wv * 8) * 64]);
#pragma unroll
    for (int p = 0; p < 2; p++)                 // B: 64 rows
      glds16(gB + (size_t)(p * 32) * K + k0, &smB[buf][(p * 32 + wv * 8) * 64]);
  };

  stage(0, 0);
  __syncthreads();
  int cur = 0;
  for (int k0 = 0; k0 < K; k0 += 64) {
    if (k0 + 64 < K) stage(cur ^ 1, k0 + 64);
    bf16x8 af[4][2], bfr[2][2];
#pragma unroll
    for (int i = 0; i < 4; i++)
#pragma unroll
      for (int c = 0; c < 2; c++)
        af[i][c] = *reinterpret_cast<const bf16x8*>(
            &smA[cur][(wm + i * 16 + lr) * 64 + ((c * 4 + g) ^ rx) * 8]);
#pragma unroll
    for (int j = 0; j < 2; j++)
#pragma unroll
      for (int c = 0; c < 2; c++)
        bfr[j][c] = *reinterpret_cast<const bf16x8*>(
            &smB[cur][(wn + j * 16 + lr) * 64 + ((c * 4 + g) ^ rx) * 8]);
#pragma unroll
    for (int c = 0; c < 2; c++)
#pragma unroll
      for (int i = 0; i < 4; i++)
#pragma unroll
        for (int j = 0; j < 2; j++)
          acc[i][j] = __builtin_amdgcn_mfma_f32_16x16x32_bf16(af[i][c], bfr[j][c], acc[i][j], 0, 0, 0);
    __syncthreads();
    cur ^= 1;
  }

  const int lcol = ln & 15, lrow4 = (ln >> 4) * 4;
#pragma unroll
  for (int i = 0; i < 4; i++) {
#pragma unroll
    for (int j = 0; j < 2; j++) {
      int gm0 = tile_m + wm + i * 16 + lrow4;
      int gn  = tile_n + wn + j * 16 + lcol;
#pragma unroll
      for (int r = 0; r < 4; r++) {
        int gm = gm0 + r;
        float val = acc[i][j][r];
        if (MODE == 0) {
          int b = gm >> 10, n = gm & 1023;
          if (gn < DIM) {
            float q = (val + qbias[gn]) * 0.125f;   // HD^-0.5
            qo[(size_t)((b * NHEAD + (gn >> 6)) * SEQ + n) * HD + (gn & 63)] = f2bf(q);
          } else if (gn < 2 * DIM) {
            int g2 = gn - DIM;
            ko[(size_t)((b * NHEAD + (g2 >> 6)) * SEQ + n) * HD + (g2 & 63)] = f2bf(val);
          } else {
            int g3 = gn - 2 * DIM;
            vto[(size_t)((b * NHEAD + (g3 >> 6)) * HD + (g3 & 63)) * SEQ + n] = f2bf(val + vbias[g3]);
          }
        } else if (MODE == 1) {   // + fp32 residual, write bf16 xres
          val += bias[gn] + ((const float*)resid)[(size_t)gm * N + gn];
          outh[(size_t)gm * N + gn] = f2bf(val);
        } else if (MODE == 2) {   // bias + tanh-GELU (max abs err ~5e-4), write bf16
          float t2 = val + bias[gn];
          float u2 = 1.5957691216f * (t2 + 0.044715f * t2 * t2 * t2);
          float e  = __expf(u2);
          float th = 1.0f - 2.0f / (e + 1.0f);
          float gl = 0.5f * t2 * (1.0f + th);
          outh[(size_t)gm * N + gn] = f2bf(gl);
        } else {                  // + bf16 residual, write fp32 final out
          val += bias[gn] + bf2f(((const unsigned short*)resid)[(size_t)gm * N + gn]);
          outf[(size_t)gm * N + gn] = val;
        }
      }
    }
  }
}

// ---------------- flash attention (R5 schedule + setprio; v_perm P-pack, max3 tree) ----------------
__global__ __launch_bounds__(512)
void attn_kernel(const unsigned short* __restrict__ qg, const unsigned short* __restrict__ kg,
                 const unsigned short* __restrict__ vtg, const float* __restrict__ rpb,
                 const int* __restrict__ amask, unsigned short* __restrict__ outh)
{
  constexpr int PSTR = 72;
  __shared__ unsigned short smK[2][64 * 64];
  __shared__ unsigned short smV[2][64 * 64];
  __shared__ unsigned short pls[8][16 * PSTR];
  const int tid = threadIdx.x;
  const int wv = tid >> 6, ln = tid & 63;
  const int bh = blockIdx.x, b = bh >> 4, h = bh & 15;
  const int q0 = blockIdx.y * 128 + wv * 16;
  const unsigned short* qb = qg  + (size_t)bh * SEQ * HD;
  const unsigned short* kb = kg  + (size_t)bh * SEQ * HD;
  const unsigned short* vb = vtg + (size_t)bh * HD * SEQ;
  const int* mp = amask + b * SEQ;
  unsigned short* myp = pls[wv];

  const int lcol = ln & 15, g = ln >> 4, lc8 = g * 8, lrow4 = g * 4;
  const int sw = (lcol & 7) << 3;
  const float* bprow = rpb + (size_t)h * SEQ * SEQ + (size_t)(q0 + lcol) * SEQ;

  const int srr = ln >> 3;
  const int scc = (ln & 7) ^ srr;

  bf16x8 aq0 = *reinterpret_cast<const bf16x8*>(qb + (size_t)(q0 + lcol) * HD + lc8);
  bf16x8 aq1 = *reinterpret_cast<const bf16x8*>(qb + (size_t)(q0 + lcol) * HD + 32 + lc8);

  f32x4 o[4] = {};
  float m = -1e30f, l = 0.f;

  auto stage = [&](int buf, int kt) {
    int row = wv * 8 + srr;
    glds16(kb + (size_t)(kt + row) * HD + scc * 8, &smK[buf][wv * 512]);
    glds16(vb + (size_t)row * SEQ + kt + scc * 8, &smV[buf][wv * 512]);
  };

  stage(0, 0);
  __syncthreads();

  for (int t = 0; t < SEQ / 64; t++) {
    const int cur = t & 1;
    const int kt = t * 64;
    float4 bv4[4]; int4 mv[4];
#pragma unroll
    for (int j = 0; j < 4; j++) {
      bv4[j] = *reinterpret_cast<const float4*>(bprow + kt + j * 16 + lrow4);
      mv[j]  = *reinterpret_cast<const int4*>(mp + kt + j * 16 + lrow4);
    }
    if (t < SEQ / 64 - 1) stage(cur ^ 1, kt + 64);

    f32x4 s[4];
    __builtin_amdgcn_s_setprio(1);
#pragma unroll
    for (int j = 0; j < 4; j++) {
      int r = j * 16 + lcol;
      bf16x8 bk0 = *reinterpret_cast<const bf16x8*>(&smK[cur][r * 64 + (lc8 ^ sw)]);
      bf16x8 bk1 = *reinterpret_cast<const bf16x8*>(&smK[cur][r * 64 + ((32 + lc8) ^ sw)]);
      f32x4 z = {0.f, 0.f, 0.f, 0.f};
      z = __builtin_amdgcn_mfma_f32_16x16x32_bf16(bk0, aq0, z, 0, 0, 0);
      z = __builtin_amdgcn_mfma_f32_16x16x32_bf16(bk1, aq1, z, 0, 0, 0);
      s[j] = z;
    }
    __builtin_amdgcn_s_setprio(0);
#pragma unroll
    for (int j = 0; j < 4; j++) {
      s[j][0] = mv[j].x ? s[j][0] + bv4[j].x : -1e30f;
      s[j][1] = mv[j].y ? s[j][1] + bv4[j].y : -1e30f;
      s[j][2] = mv[j].z ? s[j][2] + bv4[j].z : -1e30f;
      s[j][3] = mv[j].w ? s[j][3] + bv4[j].w : -1e30f;
    }
    float t0 = f3(s[0][0], s[0][1], s[0][2]);
    float t1 = f3(s[0][3], s[1][0], s[1][1]);
    float t2 = f3(s[1][2], s[1][3], s[2][0]);
    float t3 = f3(s[2][1], s[2][2], s[2][3]);
    float t4 = f3(s[3][0], s[3][1], s[3][2]);
    float pm = fmaxf(f3(t0, t1, t2), f3(t3, t4, s[3][3]));
    pm = fmaxf(pm, __shfl_xor(pm, 16));
    pm = fmaxf(pm, __shfl_xor(pm, 32));
    if (m < -1e29f || !__all(pm - m <= 8.0f)) {
      float mn = fmaxf(m, pm);
      float fr = __expf(m - mn);
      m = mn;
      l *= fr;
      float frq[4];
#pragma unroll
      for (int r = 0; r < 4; r++) frq[r] = __shfl(fr, lrow4 + r);
#pragma unroll
      for (int d = 0; d < 4; d++)
#pragma unroll
        for (int r = 0; r < 4; r++) o[d][r] *= frq[r];
    }
    float rs = 0.f;
#pragma unroll
    for (int j = 0; j < 4; j++)
#pragma unroll
      for (int r = 0; r < 4; r++) {
        float p = __expf(s[j][r] - m);
        s[j][r] = p;
        rs += p;
      }
    rs += __shfl_xor(rs, 16);
    rs += __shfl_xor(rs, 32);
    l += rs;
#pragma unroll
    for (int j = 0; j < 4; j++) {
      uint2 pw = { pkbf(s[j][0], s[j][1]), pkbf(s[j][2], s[j][3]) };
      *reinterpret_cast<uint2*>(myp + lcol * PSTR + j * 16 + lrow4) = pw;
    }
    asm volatile("s_waitcnt lgkmcnt(0)" ::: "memory");
    __builtin_amdgcn_sched_barrier(0);
    __builtin_amdgcn_s_setprio(1);
#pragma unroll
    for (int c = 0; c < 2; c++) {
      bf16x8 ap = *reinterpret_cast<const bf16x8*>(myp + lcol * PSTR + c * 32 + lc8);
#pragma unroll
      for (int d = 0; d < 4; d++) {
        int vr = d * 16 + lcol;
        bf16x8 bvv = *reinterpret_cast<const bf16x8*>(&smV[cur][vr * 64 + ((c * 32 + lc8) ^ sw)]);
        o[d] = __builtin_amdgcn_mfma_f32_16x16x32_bf16(ap, bvv, o[d], 0, 0, 0);
      }
    }
    __builtin_amdgcn_s_setprio(0);
    __syncthreads();
  }
  float linv = 1.0f / l;
  float lq[4];
#pragma unroll
  for (int r = 0; r < 4; r++) lq[r] = __shfl(linv, lrow4 + r);
#pragma unroll
  for (int d = 0; d < 4; d++)
#pragma unroll
    for (int r = 0; r < 4; r++)
      outh[(size_t)(b * SEQ + q0 + lrow4 + r) * DIM + h * HD + d * 16 + lcol] = f2bf(o[d][r] * lq[r]);
}

// ---------------- host ----------------
extern "C" void kernel_launch(void* const* d_in, const int* in_sizes, int n_in,
                              void* d_out, int out_size, void* d_ws, size_t ws_size,
                              hipStream_t stream)
{
  const float* x      = (const float*)d_in[0];
  const float* rpb    = (const float*)d_in[1];
  const int*   amask  = (const int*)d_in[2];
  const float* n1w    = (const float*)d_in[3];
  const float* n1b    = (const float*)d_in[4];
  const float* qkv_w  = (const float*)d_in[5];
  const float* q_bias = (const float*)d_in[6];
  const float* v_bias = (const float*)d_in[7];
  const float* proj_w = (const float*)d_in[8];
  const float* proj_b = (const float*)d_in[9];
  const float* n2w    = (const float*)d_in[10];
  const float* n2b    = (const float*)d_in[11];
  const float* w1     = (const float*)d_in[12];
  const float* b1     = (const float*)d_in[13];
  const float* w2     = (const float*)d_in[14];
  const float* b2     = (const float*)d_in[15];
  float* out = (float*)d_out;

  char* ws = (char*)d_ws;
  size_t off = 0;
  auto alloc = [&](size_t bytes) { char* p = ws + off; off += (bytes + 255) & ~(size_t)255; return p; };
  unsigned short* xn1    = (unsigned short*)alloc((size_t)ROWS * DIM * 2);
  unsigned short* xn2    = (unsigned short*)alloc((size_t)ROWS * DIM * 2);
  unsigned short* wqkv_h = (unsigned short*)alloc((size_t)3 * DIM * DIM * 2);
  unsigned short* wproj_h= (unsigned short*)alloc((size_t)DIM * DIM * 2);
  unsigned short* w1_h   = (unsigned short*)alloc((size_t)HIDDEN * DIM * 2);
  unsigned short* w2_h   = (unsigned short*)alloc((size_t)DIM * HIDDEN * 2);
  unsigned short* qh     = (unsigned short*)alloc((size_t)ROWS * DIM * 2);
  unsigned short* kh     = (unsigned short*)alloc((size_t)ROWS * DIM * 2);
  unsigned short* vth    = (unsigned short*)alloc((size_t)ROWS * DIM * 2);
  unsigned short* attn_h = (unsigned short*)alloc((size_t)ROWS * DIM * 2);
  unsigned short* xresh  = (unsigned short*)alloc((size_t)ROWS * DIM * 2);   // bf16 residual
  unsigned short* hmid   = (unsigned short*)alloc((size_t)ROWS * HIDDEN * 2);

  // all weight conversions in one launch
  cvt_all<<<2048, 256, 0, stream>>>(qkv_w, proj_w, w1, w2, wqkv_h, wproj_h, w1_h, w2_h);

  // LN1 (fp32 in)
  ln_kernel<false><<<ROWS, 256, 0, stream>>>(x, n1w, n1b, xn1);
  // QKV GEMM (M=4096, N=3072, K=1024) -- BK=64, 1536 blocks, XCD-swizzled
  gemm64k<0><<<dim3(ROWS / 128, 3 * DIM / 64), 256, 0, stream>>>(
      xn1, wqkv_h, DIM, 3 * DIM, nullptr, nullptr, nullptr, nullptr, qh, kh, vth, q_bias, v_bias);
  // attention -- grid (bh, qblock): XCD = bh%8 -> per-head K/V/rpb locality
  attn_kernel<<<dim3(BATCH * NHEAD, SEQ / 128), 512, 0, stream>>>(qh, kh, vth, rpb, amask, attn_h);
  // proj + residual -> xres (bf16) -- BK=64, 512 blocks, XCD-swizzled
  gemm64k<1><<<dim3(ROWS / 128, DIM / 64), 256, 0, stream>>>(
      attn_h, wproj_h, DIM, DIM, proj_b, x, nullptr, xresh, nullptr, nullptr, nullptr, nullptr, nullptr);
  // LN2 (bf16 in)
  ln_kernel<true><<<ROWS, 256, 0, stream>>>(xresh, n2w, n2b, xn2);
  // MLP1 + tanh-GELU -- BK=64, 2048 blocks, XCD-swizzled
  gemm64k<2><<<dim3(ROWS / 128, HIDDEN / 64), 256, 0, stream>>>(
      xn2, w1_h, DIM, HIDDEN, b1, nullptr, nullptr, hmid, nullptr, nullptr, nullptr, nullptr, nullptr);
  // MLP2 + bf16 residual -> out (fp32) -- BK=64, 512 blocks, XCD-swizzled
  gemm64k<3><<<dim3(ROWS / 128, DIM / 64), 256, 0, stream>>>(
      hmid, w2_h, HIDDEN, DIM, b2, xresh, out, nullptr, nullptr, nullptr, nullptr, nullptr, nullptr);
}

// Round 20
// 259.183 us; speedup vs baseline: 1.0303x; 1.0303x over previous
//
#include <hip/hip_runtime.h>
#include <math.h>

#define DIM 1024
#define NHEAD 16
#define HD 64
#define HIDDEN 4096
#define SEQ 1024
#define BATCH 4
#define ROWS (BATCH*SEQ)   // 4096 tokens

typedef __attribute__((ext_vector_type(8))) short bf16x8;
typedef __attribute__((ext_vector_type(4))) float f32x4;
typedef __attribute__((ext_vector_type(4))) unsigned short us4;

__device__ __forceinline__ unsigned short f2bf(float f) {
  unsigned u = __builtin_bit_cast(unsigned, f);
  u += 0x7fffu + ((u >> 16) & 1u);           // round-to-nearest-even
  return (unsigned short)(u >> 16);
}

__device__ __forceinline__ float bf2f(unsigned short h) {
  unsigned u = (unsigned)h << 16;
  return __builtin_bit_cast(float, u);
}

// pack two f32 -> (bf16(b)<<16)|bf16(a), round-half-up (err <= 2^-9 rel): 2 add + 1 perm
__device__ __forceinline__ unsigned pkbf(float a, float b) {
  unsigned ua = __builtin_bit_cast(unsigned, a) + 0x8000u;
  unsigned ub = __builtin_bit_cast(unsigned, b) + 0x8000u;
  return __builtin_amdgcn_perm(ub, ua, 0x07060302u);  // [ub.b3 ub.b2 ua.b3 ua.b2]
}

__device__ __forceinline__ float f3(float a, float b, float c) {  // fuses to v_max3_f32
  return fmaxf(fmaxf(a, b), c);
}

__device__ __forceinline__ void glds16(const void* g, void* l) {
  __builtin_amdgcn_global_load_lds((const __attribute__((address_space(1))) void*)g,
                                   (__attribute__((address_space(3))) void*)l,
                                   16, 0, 0);
}

// ---------------- fp32 -> bf16 weight conversion (all 4 weights, one launch) ----------------
__global__ void cvt_all(const float* __restrict__ a, const float* __restrict__ b,
                        const float* __restrict__ c, const float* __restrict__ d,
                        unsigned short* __restrict__ oa, unsigned short* __restrict__ ob,
                        unsigned short* __restrict__ oc, unsigned short* __restrict__ od) {
  const int na = 3 * DIM * DIM / 4, nb = DIM * DIM / 4, nc = HIDDEN * DIM / 4, nd = DIM * HIDDEN / 4;
  const int total = na + nb + nc + nd;
  for (int i = blockIdx.x * blockDim.x + threadIdx.x; i < total; i += gridDim.x * blockDim.x) {
    const float* in; unsigned short* out; int j = i;
    if (j < na)             { in = a; out = oa; }
    else if ((j -= na) < nb){ in = b; out = ob; }
    else if ((j -= nb) < nc){ in = c; out = oc; }
    else                    { j -= nc; in = d; out = od; }
    float4 v = reinterpret_cast<const float4*>(in)[j];
    us4 o = { f2bf(v.x), f2bf(v.y), f2bf(v.z), f2bf(v.w) };
    reinterpret_cast<us4*>(out)[j] = o;
  }
}

// ---------------- LayerNorm: fp32 or bf16 row -> bf16 normalized ----------------
template<bool IN_BF16>
__global__ void ln_kernel(const void* __restrict__ xv, const float* __restrict__ w,
                          const float* __restrict__ b, unsigned short* __restrict__ out) {
  int row = blockIdx.x;
  int t = threadIdx.x;
  float4 v;
  if (IN_BF16) {
    const unsigned short* xr = (const unsigned short*)xv + (size_t)row * DIM;
    us4 hv = *reinterpret_cast<const us4*>(xr + t * 4);
    v.x = bf2f(hv[0]); v.y = bf2f(hv[1]); v.z = bf2f(hv[2]); v.w = bf2f(hv[3]);
  } else {
    const float* xr = (const float*)xv + (size_t)row * DIM;
    v = *reinterpret_cast<const float4*>(xr + t * 4);
  }
  float s  = v.x + v.y + v.z + v.w;
  float s2 = v.x*v.x + v.y*v.y + v.z*v.z + v.w*v.w;
#pragma unroll
  for (int m = 1; m < 64; m <<= 1) { s += __shfl_xor(s, m); s2 += __shfl_xor(s2, m); }
  __shared__ float red[8];
  int wv = t >> 6, ln = t & 63;
  if (ln == 0) { red[wv] = s; red[4 + wv] = s2; }
  __syncthreads();
  s  = red[0] + red[1] + red[2] + red[3];
  s2 = red[4] + red[5] + red[6] + red[7];
  float mu  = s * (1.0f / DIM);
  float var = s2 * (1.0f / DIM) - mu * mu;
  float rs  = rsqrtf(var + 1e-5f);
  float4 wv4 = *reinterpret_cast<const float4*>(w + t * 4);
  float4 bv4 = *reinterpret_cast<const float4*>(b + t * 4);
  us4 o = { f2bf((v.x - mu) * rs * wv4.x + bv4.x),
            f2bf((v.y - mu) * rs * wv4.y + bv4.y),
            f2bf((v.z - mu) * rs * wv4.z + bv4.z),
            f2bf((v.w - mu) * rs * wv4.w + bv4.w) };
  *reinterpret_cast<us4*>(out + (size_t)row * DIM + t * 4) = o;
}

// ---------------- 128x64 bf16 NT GEMM, BK=64 2-phase dbuf (ALL four GEMMs) ----------------
// R13/R14-proven structure; NO XCD swizzle (R19: chunked remap put all of A in one XCD's
// L2 -> FETCH 42->102MB, -10us. Default bx%8 mapping keeps per-XCD A footprint at 1MB).
// MODE 0: QKV  -> q (bias+scale), k, vT (bf16)
// MODE 1: proj -> xres_bf16 = acc + bias + x_fp32
// MODE 2: mlp1 -> outh = gelu(acc + bias) (bf16, tanh-approx)
// MODE 3: mlp2 -> out_fp32 = acc + bias + xres_bf16
template<int MODE>
__global__ __launch_bounds__(256)
void gemm64k(const unsigned short* __restrict__ A, const unsigned short* __restrict__ Bw,
             int K, int N,
             const float* __restrict__ bias, const void* __restrict__ resid,
             float* __restrict__ outf, unsigned short* __restrict__ outh,
             unsigned short* __restrict__ qo, unsigned short* __restrict__ ko,
             unsigned short* __restrict__ vto,
             const float* __restrict__ qbias, const float* __restrict__ vbias)
{
  __shared__ unsigned short smA[2][128 * 64];   // 16KB each
  __shared__ unsigned short smB[2][64 * 64];    // 8KB each
  const int tid = threadIdx.x;
  const int wv = tid >> 6, ln = tid & 63;
  const int tile_m = blockIdx.x * 128, tile_n = blockIdx.y * 64;
  const int wm = (wv >> 1) * 64, wn = (wv & 1) * 32;

  const int srow8 = ln >> 3;                    // row in 8-row group
  const int sch8  = (ln & 7) ^ srow8;           // pre-swizzled global chunk (of 8)
  const unsigned short* gA = A  + (size_t)(tile_m + wv * 8 + srow8) * K + sch8 * 8;
  const unsigned short* gB = Bw + (size_t)(tile_n + wv * 8 + srow8) * K + sch8 * 8;

  f32x4 acc[4][2] = {};
  const int lr = ln & 15, g = ln >> 4;
  const int rx = lr & 7;                        // read-side row XOR key

  auto stage = [&](int buf, int k0) {
#pragma unroll
    for (int p = 0; p < 4; p++)                 // A: 128 rows
      glds16(gA + (size_t)(p * 32) * K + k0, &smA[buf][(p * 32 + wv * 8) * 64]);
#pragma unroll
    for (int p = 0; p < 2; p++)                 // B: 64 rows
      glds16(gB + (size_t)(p * 32) * K + k0, &smB[buf][(p * 32 + wv * 8) * 64]);
  };

  stage(0, 0);
  __syncthreads();
  int cur = 0;
  for (int k0 = 0; k0 < K; k0 += 64) {
    if (k0 + 64 < K) stage(cur ^ 1, k0 + 64);
    bf16x8 af[4][2], bfr[2][2];
#pragma unroll
    for (int i = 0; i < 4; i++)
#pragma unroll
      for (int c = 0; c < 2; c++)
        af[i][c] = *reinterpret_cast<const bf16x8*>(
            &smA[cur][(wm + i * 16 + lr) * 64 + ((c * 4 + g) ^ rx) * 8]);
#pragma unroll
    for (int j = 0; j < 2; j++)
#pragma unroll
      for (int c = 0; c < 2; c++)
        bfr[j][c] = *reinterpret_cast<const bf16x8*>(
            &smB[cur][(wn + j * 16 + lr) * 64 + ((c * 4 + g) ^ rx) * 8]);
#pragma unroll
    for (int c = 0; c < 2; c++)
#pragma unroll
      for (int i = 0; i < 4; i++)
#pragma unroll
        for (int j = 0; j < 2; j++)
          acc[i][j] = __builtin_amdgcn_mfma_f32_16x16x32_bf16(af[i][c], bfr[j][c], acc[i][j], 0, 0, 0);
    __syncthreads();
    cur ^= 1;
  }

  const int lcol = ln & 15, lrow4 = (ln >> 4) * 4;
#pragma unroll
  for (int i = 0; i < 4; i++) {
#pragma unroll
    for (int j = 0; j < 2; j++) {
      int gm0 = tile_m + wm + i * 16 + lrow4;
      int gn  = tile_n + wn + j * 16 + lcol;
#pragma unroll
      for (int r = 0; r < 4; r++) {
        int gm = gm0 + r;
        float val = acc[i][j][r];
        if (MODE == 0) {
          int b = gm >> 10, n = gm & 1023;
          if (gn < DIM) {
            float q = (val + qbias[gn]) * 0.125f;   // HD^-0.5
            qo[(size_t)((b * NHEAD + (gn >> 6)) * SEQ + n) * HD + (gn & 63)] = f2bf(q);
          } else if (gn < 2 * DIM) {
            int g2 = gn - DIM;
            ko[(size_t)((b * NHEAD + (g2 >> 6)) * SEQ + n) * HD + (g2 & 63)] = f2bf(val);
          } else {
            int g3 = gn - 2 * DIM;
            vto[(size_t)((b * NHEAD + (g3 >> 6)) * HD + (g3 & 63)) * SEQ + n] = f2bf(val + vbias[g3]);
          }
        } else if (MODE == 1) {   // + fp32 residual, write bf16 xres
          val += bias[gn] + ((const float*)resid)[(size_t)gm * N + gn];
          outh[(size_t)gm * N + gn] = f2bf(val);
        } else if (MODE == 2) {   // bias + tanh-GELU (max abs err ~5e-4), write bf16
          float t2 = val + bias[gn];
          float u2 = 1.5957691216f * (t2 + 0.044715f * t2 * t2 * t2);
          float e  = __expf(u2);
          float th = 1.0f - 2.0f / (e + 1.0f);
          float gl = 0.5f * t2 * (1.0f + th);
          outh[(size_t)gm * N + gn] = f2bf(gl);
        } else {                  // + bf16 residual, write fp32 final out
          val += bias[gn] + bf2f(((const unsigned short*)resid)[(size_t)gm * N + gn]);
          outf[(size_t)gm * N + gn] = val;
        }
      }
    }
  }
}

// ---------------- flash attention (R5 schedule + setprio; v_perm P-pack, max3 tree) ----------------
__global__ __launch_bounds__(512)
void attn_kernel(const unsigned short* __restrict__ qg, const unsigned short* __restrict__ kg,
                 const unsigned short* __restrict__ vtg, const float* __restrict__ rpb,
                 const int* __restrict__ amask, unsigned short* __restrict__ outh)
{
  constexpr int PSTR = 72;
  __shared__ unsigned short smK[2][64 * 64];
  __shared__ unsigned short smV[2][64 * 64];
  __shared__ unsigned short pls[8][16 * PSTR];
  const int tid = threadIdx.x;
  const int wv = tid >> 6, ln = tid & 63;
  const int bh = blockIdx.x, b = bh >> 4, h = bh & 15;
  const int q0 = blockIdx.y * 128 + wv * 16;
  const unsigned short* qb = qg  + (size_t)bh * SEQ * HD;
  const unsigned short* kb = kg  + (size_t)bh * SEQ * HD;
  const unsigned short* vb = vtg + (size_t)bh * HD * SEQ;
  const int* mp = amask + b * SEQ;
  unsigned short* myp = pls[wv];

  const int lcol = ln & 15, g = ln >> 4, lc8 = g * 8, lrow4 = g * 4;
  const int sw = (lcol & 7) << 3;
  const float* bprow = rpb + (size_t)h * SEQ * SEQ + (size_t)(q0 + lcol) * SEQ;

  const int srr = ln >> 3;
  const int scc = (ln & 7) ^ srr;

  bf16x8 aq0 = *reinterpret_cast<const bf16x8*>(qb + (size_t)(q0 + lcol) * HD + lc8);
  bf16x8 aq1 = *reinterpret_cast<const bf16x8*>(qb + (size_t)(q0 + lcol) * HD + 32 + lc8);

  f32x4 o[4] = {};
  float m = -1e30f, l = 0.f;

  auto stage = [&](int buf, int kt) {
    int row = wv * 8 + srr;
    glds16(kb + (size_t)(kt + row) * HD + scc * 8, &smK[buf][wv * 512]);
    glds16(vb + (size_t)row * SEQ + kt + scc * 8, &smV[buf][wv * 512]);
  };

  stage(0, 0);
  __syncthreads();

  for (int t = 0; t < SEQ / 64; t++) {
    const int cur = t & 1;
    const int kt = t * 64;
    float4 bv4[4]; int4 mv[4];
#pragma unroll
    for (int j = 0; j < 4; j++) {
      bv4[j] = *reinterpret_cast<const float4*>(bprow + kt + j * 16 + lrow4);
      mv[j]  = *reinterpret_cast<const int4*>(mp + kt + j * 16 + lrow4);
    }
    if (t < SEQ / 64 - 1) stage(cur ^ 1, kt + 64);

    f32x4 s[4];
    __builtin_amdgcn_s_setprio(1);
#pragma unroll
    for (int j = 0; j < 4; j++) {
      int r = j * 16 + lcol;
      bf16x8 bk0 = *reinterpret_cast<const bf16x8*>(&smK[cur][r * 64 + (lc8 ^ sw)]);
      bf16x8 bk1 = *reinterpret_cast<const bf16x8*>(&smK[cur][r * 64 + ((32 + lc8) ^ sw)]);
      f32x4 z = {0.f, 0.f, 0.f, 0.f};
      z = __builtin_amdgcn_mfma_f32_16x16x32_bf16(bk0, aq0, z, 0, 0, 0);
      z = __builtin_amdgcn_mfma_f32_16x16x32_bf16(bk1, aq1, z, 0, 0, 0);
      s[j] = z;
    }
    __builtin_amdgcn_s_setprio(0);
#pragma unroll
    for (int j = 0; j < 4; j++) {
      s[j][0] = mv[j].x ? s[j][0] + bv4[j].x : -1e30f;
      s[j][1] = mv[j].y ? s[j][1] + bv4[j].y : -1e30f;
      s[j][2] = mv[j].z ? s[j][2] + bv4[j].z : -1e30f;
      s[j][3] = mv[j].w ? s[j][3] + bv4[j].w : -1e30f;
    }
    float t0 = f3(s[0][0], s[0][1], s[0][2]);
    float t1 = f3(s[0][3], s[1][0], s[1][1]);
    float t2 = f3(s[1][2], s[1][3], s[2][0]);
    float t3 = f3(s[2][1], s[2][2], s[2][3]);
    float t4 = f3(s[3][0], s[3][1], s[3][2]);
    float pm = fmaxf(f3(t0, t1, t2), f3(t3, t4, s[3][3]));
    pm = fmaxf(pm, __shfl_xor(pm, 16));
    pm = fmaxf(pm, __shfl_xor(pm, 32));
    if (m < -1e29f || !__all(pm - m <= 8.0f)) {
      float mn = fmaxf(m, pm);
      float fr = __expf(m - mn);
      m = mn;
      l *= fr;
      float frq[4];
#pragma unroll
      for (int r = 0; r < 4; r++) frq[r] = __shfl(fr, lrow4 + r);
#pragma unroll
      for (int d = 0; d < 4; d++)
#pragma unroll
        for (int r = 0; r < 4; r++) o[d][r] *= frq[r];
    }
    float rs = 0.f;
#pragma unroll
    for (int j = 0; j < 4; j++)
#pragma unroll
      for (int r = 0; r < 4; r++) {
        float p = __expf(s[j][r] - m);
        s[j][r] = p;
        rs += p;
      }
    rs += __shfl_xor(rs, 16);
    rs += __shfl_xor(rs, 32);
    l += rs;
#pragma unroll
    for (int j = 0; j < 4; j++) {
      uint2 pw = { pkbf(s[j][0], s[j][1]), pkbf(s[j][2], s[j][3]) };
      *reinterpret_cast<uint2*>(myp + lcol * PSTR + j * 16 + lrow4) = pw;
    }
    asm volatile("s_waitcnt lgkmcnt(0)" ::: "memory");
    __builtin_amdgcn_sched_barrier(0);
    __builtin_amdgcn_s_setprio(1);
#pragma unroll
    for (int c = 0; c < 2; c++) {
      bf16x8 ap = *reinterpret_cast<const bf16x8*>(myp + lcol * PSTR + c * 32 + lc8);
#pragma unroll
      for (int d = 0; d < 4; d++) {
        int vr = d * 16 + lcol;
        bf16x8 bvv = *reinterpret_cast<const bf16x8*>(&smV[cur][vr * 64 + ((c * 32 + lc8) ^ sw)]);
        o[d] = __builtin_amdgcn_mfma_f32_16x16x32_bf16(ap, bvv, o[d], 0, 0, 0);
      }
    }
    __builtin_amdgcn_s_setprio(0);
    __syncthreads();
  }
  float linv = 1.0f / l;
  float lq[4];
#pragma unroll
  for (int r = 0; r < 4; r++) lq[r] = __shfl(linv, lrow4 + r);
#pragma unroll
  for (int d = 0; d < 4; d++)
#pragma unroll
    for (int r = 0; r < 4; r++)
      outh[(size_t)(b * SEQ + q0 + lrow4 + r) * DIM + h * HD + d * 16 + lcol] = f2bf(o[d][r] * lq[r]);
}

// ---------------- host ----------------
extern "C" void kernel_launch(void* const* d_in, const int* in_sizes, int n_in,
                              void* d_out, int out_size, void* d_ws, size_t ws_size,
                              hipStream_t stream)
{
  const float* x      = (const float*)d_in[0];
  const float* rpb    = (const float*)d_in[1];
  const int*   amask  = (const int*)d_in[2];
  const float* n1w    = (const float*)d_in[3];
  const float* n1b    = (const float*)d_in[4];
  const float* qkv_w  = (const float*)d_in[5];
  const float* q_bias = (const float*)d_in[6];
  const float* v_bias = (const float*)d_in[7];
  const float* proj_w = (const float*)d_in[8];
  const float* proj_b = (const float*)d_in[9];
  const float* n2w    = (const float*)d_in[10];
  const float* n2b    = (const float*)d_in[11];
  const float* w1     = (const float*)d_in[12];
  const float* b1     = (const float*)d_in[13];
  const float* w2     = (const float*)d_in[14];
  const float* b2     = (const float*)d_in[15];
  float* out = (float*)d_out;

  char* ws = (char*)d_ws;
  size_t off = 0;
  auto alloc = [&](size_t bytes) { char* p = ws + off; off += (bytes + 255) & ~(size_t)255; return p; };
  unsigned short* xn1    = (unsigned short*)alloc((size_t)ROWS * DIM * 2);
  unsigned short* xn2    = (unsigned short*)alloc((size_t)ROWS * DIM * 2);
  unsigned short* wqkv_h = (unsigned short*)alloc((size_t)3 * DIM * DIM * 2);
  unsigned short* wproj_h= (unsigned short*)alloc((size_t)DIM * DIM * 2);
  unsigned short* w1_h   = (unsigned short*)alloc((size_t)HIDDEN * DIM * 2);
  unsigned short* w2_h   = (unsigned short*)alloc((size_t)DIM * HIDDEN * 2);
  unsigned short* qh     = (unsigned short*)alloc((size_t)ROWS * DIM * 2);
  unsigned short* kh     = (unsigned short*)alloc((size_t)ROWS * DIM * 2);
  unsigned short* vth    = (unsigned short*)alloc((size_t)ROWS * DIM * 2);
  unsigned short* attn_h = (unsigned short*)alloc((size_t)ROWS * DIM * 2);
  unsigned short* xresh  = (unsigned short*)alloc((size_t)ROWS * DIM * 2);   // bf16 residual
  unsigned short* hmid   = (unsigned short*)alloc((size_t)ROWS * HIDDEN * 2);

  // all weight conversions in one launch
  cvt_all<<<2048, 256, 0, stream>>>(qkv_w, proj_w, w1, w2, wqkv_h, wproj_h, w1_h, w2_h);

  // LN1 (fp32 in)
  ln_kernel<false><<<ROWS, 256, 0, stream>>>(x, n1w, n1b, xn1);
  // QKV GEMM (M=4096, N=3072, K=1024) -- BK=64, 1536 blocks
  gemm64k<0><<<dim3(ROWS / 128, 3 * DIM / 64), 256, 0, stream>>>(
      xn1, wqkv_h, DIM, 3 * DIM, nullptr, nullptr, nullptr, nullptr, qh, kh, vth, q_bias, v_bias);
  // attention -- grid (bh, qblock): XCD = bh%8 -> per-head K/V/rpb locality
  attn_kernel<<<dim3(BATCH * NHEAD, SEQ / 128), 512, 0, stream>>>(qh, kh, vth, rpb, amask, attn_h);
  // proj + residual -> xres (bf16) -- BK=64, 512 blocks
  gemm64k<1><<<dim3(ROWS / 128, DIM / 64), 256, 0, stream>>>(
      attn_h, wproj_h, DIM, DIM, proj_b, x, nullptr, xresh, nullptr, nullptr, nullptr, nullptr, nullptr);
  // LN2 (bf16 in)
  ln_kernel<true><<<ROWS, 256, 0, stream>>>(xresh, n2w, n2b, xn2);
  // MLP1 + tanh-GELU -- BK=64, 2048 blocks
  gemm64k<2><<<dim3(ROWS / 128, HIDDEN / 64), 256, 0, stream>>>(
      xn2, w1_h, DIM, HIDDEN, b1, nullptr, nullptr, hmid, nullptr, nullptr, nullptr, nullptr, nullptr);
  // MLP2 + bf16 residual -> out (fp32) -- BK=64, 512 blocks
  gemm64k<3><<<dim3(ROWS / 128, DIM / 64), 256, 0, stream>>>(
      hmid, w2_h, HIDDEN, DIM, b2, xresh, out, nullptr, nullptr, nullptr, nullptr, nullptr, nullptr);
}

// Round 21
// 253.081 us; speedup vs baseline: 1.0551x; 1.0241x over previous
//
#include <hip/hip_runtime.h>
#include <math.h>

#define DIM 1024
#define NHEAD 16
#define HD 64
#define HIDDEN 4096
#define SEQ 1024
#define BATCH 4
#define ROWS (BATCH*SEQ)   // 4096 tokens

typedef __attribute__((ext_vector_type(8))) short bf16x8;
typedef __attribute__((ext_vector_type(4))) float f32x4;
typedef __attribute__((ext_vector_type(4))) unsigned short us4;

__device__ __forceinline__ unsigned short f2bf(float f) {
  unsigned u = __builtin_bit_cast(unsigned, f);
  u += 0x7fffu + ((u >> 16) & 1u);           // round-to-nearest-even
  return (unsigned short)(u >> 16);
}

__device__ __forceinline__ float bf2f(unsigned short h) {
  unsigned u = (unsigned)h << 16;
  return __builtin_bit_cast(float, u);
}

// pack two f32 -> (bf16(b)<<16)|bf16(a), round-half-up (err <= 2^-9 rel): 2 add + 1 perm
__device__ __forceinline__ unsigned pkbf(float a, float b) {
  unsigned ua = __builtin_bit_cast(unsigned, a) + 0x8000u;
  unsigned ub = __builtin_bit_cast(unsigned, b) + 0x8000u;
  return __builtin_amdgcn_perm(ub, ua, 0x07060302u);  // [ub.b3 ub.b2 ua.b3 ua.b2]
}

__device__ __forceinline__ float f3(float a, float b, float c) {  // fuses to v_max3_f32
  return fmaxf(fmaxf(a, b), c);
}

__device__ __forceinline__ void glds16(const void* g, void* l) {
  __builtin_amdgcn_global_load_lds((const __attribute__((address_space(1))) void*)g,
                                   (__attribute__((address_space(3))) void*)l,
                                   16, 0, 0);
}

// ---------------- fp32 -> bf16 weight conversion (all 4 weights, one launch) ----------------
__global__ void cvt_all(const float* __restrict__ a, const float* __restrict__ b,
                        const float* __restrict__ c, const float* __restrict__ d,
                        unsigned short* __restrict__ oa, unsigned short* __restrict__ ob,
                        unsigned short* __restrict__ oc, unsigned short* __restrict__ od) {
  const int na = 3 * DIM * DIM / 4, nb = DIM * DIM / 4, nc = HIDDEN * DIM / 4, nd = DIM * HIDDEN / 4;
  const int total = na + nb + nc + nd;
  for (int i = blockIdx.x * blockDim.x + threadIdx.x; i < total; i += gridDim.x * blockDim.x) {
    const float* in; unsigned short* out; int j = i;
    if (j < na)             { in = a; out = oa; }
    else if ((j -= na) < nb){ in = b; out = ob; }
    else if ((j -= nb) < nc){ in = c; out = oc; }
    else                    { j -= nc; in = d; out = od; }
    float4 v = reinterpret_cast<const float4*>(in)[j];
    us4 o = { f2bf(v.x), f2bf(v.y), f2bf(v.z), f2bf(v.w) };
    reinterpret_cast<us4*>(out)[j] = o;
  }
}

// ---------------- LayerNorm: fp32 or bf16 row -> bf16 normalized ----------------
template<bool IN_BF16>
__global__ void ln_kernel(const void* __restrict__ xv, const float* __restrict__ w,
                          const float* __restrict__ b, unsigned short* __restrict__ out) {
  int row = blockIdx.x;
  int t = threadIdx.x;
  float4 v;
  if (IN_BF16) {
    const unsigned short* xr = (const unsigned short*)xv + (size_t)row * DIM;
    us4 hv = *reinterpret_cast<const us4*>(xr + t * 4);
    v.x = bf2f(hv[0]); v.y = bf2f(hv[1]); v.z = bf2f(hv[2]); v.w = bf2f(hv[3]);
  } else {
    const float* xr = (const float*)xv + (size_t)row * DIM;
    v = *reinterpret_cast<const float4*>(xr + t * 4);
  }
  float s  = v.x + v.y + v.z + v.w;
  float s2 = v.x*v.x + v.y*v.y + v.z*v.z + v.w*v.w;
#pragma unroll
  for (int m = 1; m < 64; m <<= 1) { s += __shfl_xor(s, m); s2 += __shfl_xor(s2, m); }
  __shared__ float red[8];
  int wv = t >> 6, ln = t & 63;
  if (ln == 0) { red[wv] = s; red[4 + wv] = s2; }
  __syncthreads();
  s  = red[0] + red[1] + red[2] + red[3];
  s2 = red[4] + red[5] + red[6] + red[7];
  float mu  = s * (1.0f / DIM);
  float var = s2 * (1.0f / DIM) - mu * mu;
  float rs  = rsqrtf(var + 1e-5f);
  float4 wv4 = *reinterpret_cast<const float4*>(w + t * 4);
  float4 bv4 = *reinterpret_cast<const float4*>(b + t * 4);
  us4 o = { f2bf((v.x - mu) * rs * wv4.x + bv4.x),
            f2bf((v.y - mu) * rs * wv4.y + bv4.y),
            f2bf((v.z - mu) * rs * wv4.z + bv4.z),
            f2bf((v.w - mu) * rs * wv4.w + bv4.w) };
  *reinterpret_cast<us4*>(out + (size_t)row * DIM + t * 4) = o;
}

// ---------------- 128x128 bf16 NT GEMM, BK=64, 64x64/wave (QKV + MLP1) ----------------
// LDS-issue-bound fix: gemm64k's 64x32/wave = 12 b128 reads per 16 MFMAs -> MfmaUtil
// ceiling 80/384 = 21% (measured 20-21%). 64x64/wave = 16 reads per 32 MFMAs ->
// ceiling 160/512 = 31%. Same 2-phase dbuf schedule, BK=64 cadence, XOR swizzle
// chunk^(row&7) both sides (rule #21). LDS 64KB -> 2 blocks/CU.
// MODE 0: QKV -> q (bias+scale), k, vT.  MODE 2: mlp1 -> tanh-GELU (bf16).
template<int MODE>
__global__ __launch_bounds__(256)
void gemm128k(const unsigned short* __restrict__ A, const unsigned short* __restrict__ Bw,
              int K, int N,
              const float* __restrict__ bias,
              unsigned short* __restrict__ outh,
              unsigned short* __restrict__ qo, unsigned short* __restrict__ ko,
              unsigned short* __restrict__ vto,
              const float* __restrict__ qbias, const float* __restrict__ vbias)
{
  __shared__ unsigned short smA[2][128 * 64];   // 16KB each
  __shared__ unsigned short smB[2][128 * 64];   // 16KB each
  const int tid = threadIdx.x;
  const int wv = tid >> 6, ln = tid & 63;
  const int tile_m = blockIdx.x * 128, tile_n = blockIdx.y * 128;
  const int wm = (wv >> 1) * 64, wn = (wv & 1) * 64;

  const int srow8 = ln >> 3;                    // row in 8-row group
  const int sch8  = (ln & 7) ^ srow8;           // pre-swizzled global chunk (of 8)
  const unsigned short* gA = A  + (size_t)(tile_m + wv * 8 + srow8) * K + sch8 * 8;
  const unsigned short* gB = Bw + (size_t)(tile_n + wv * 8 + srow8) * K + sch8 * 8;

  f32x4 acc[4][4] = {};
  const int lr = ln & 15, g = ln >> 4;
  const int rx = lr & 7;                        // read-side row XOR key

  auto stage = [&](int buf, int k0) {
#pragma unroll
    for (int p = 0; p < 4; p++)                 // A: 128 rows
      glds16(gA + (size_t)(p * 32) * K + k0, &smA[buf][(p * 32 + wv * 8) * 64]);
#pragma unroll
    for (int p = 0; p < 4; p++)                 // B: 128 rows
      glds16(gB + (size_t)(p * 32) * K + k0, &smB[buf][(p * 32 + wv * 8) * 64]);
  };

  stage(0, 0);
  __syncthreads();
  int cur = 0;
  for (int k0 = 0; k0 < K; k0 += 64) {
    if (k0 + 64 < K) stage(cur ^ 1, k0 + 64);
    bf16x8 af[4][2], bfr[4][2];
#pragma unroll
    for (int i = 0; i < 4; i++)
#pragma unroll
      for (int c = 0; c < 2; c++)
        af[i][c] = *reinterpret_cast<const bf16x8*>(
            &smA[cur][(wm + i * 16 + lr) * 64 + ((c * 4 + g) ^ rx) * 8]);
#pragma unroll
    for (int j = 0; j < 4; j++)
#pragma unroll
      for (int c = 0; c < 2; c++)
        bfr[j][c] = *reinterpret_cast<const bf16x8*>(
            &smB[cur][(wn + j * 16 + lr) * 64 + ((c * 4 + g) ^ rx) * 8]);
#pragma unroll
    for (int c = 0; c < 2; c++)
#pragma unroll
      for (int i = 0; i < 4; i++)
#pragma unroll
        for (int j = 0; j < 4; j++)
          acc[i][j] = __builtin_amdgcn_mfma_f32_16x16x32_bf16(af[i][c], bfr[j][c], acc[i][j], 0, 0, 0);
    __syncthreads();
    cur ^= 1;
  }

  const int lcol = ln & 15, lrow4 = (ln >> 4) * 4;
#pragma unroll
  for (int i = 0; i < 4; i++) {
#pragma unroll
    for (int j = 0; j < 4; j++) {
      int gm0 = tile_m + wm + i * 16 + lrow4;
      int gn  = tile_n + wn + j * 16 + lcol;
#pragma unroll
      for (int r = 0; r < 4; r++) {
        int gm = gm0 + r;
        float val = acc[i][j][r];
        if (MODE == 0) {
          int b = gm >> 10, n = gm & 1023;
          if (gn < DIM) {
            float q = (val + qbias[gn]) * 0.125f;   // HD^-0.5
            qo[(size_t)((b * NHEAD + (gn >> 6)) * SEQ + n) * HD + (gn & 63)] = f2bf(q);
          } else if (gn < 2 * DIM) {
            int g2 = gn - DIM;
            ko[(size_t)((b * NHEAD + (g2 >> 6)) * SEQ + n) * HD + (g2 & 63)] = f2bf(val);
          } else {
            int g3 = gn - 2 * DIM;
            vto[(size_t)((b * NHEAD + (g3 >> 6)) * HD + (g3 & 63)) * SEQ + n] = f2bf(val + vbias[g3]);
          }
        } else {                  // bias + tanh-GELU, write bf16
          float t2 = val + bias[gn];
          float u2 = 1.5957691216f * (t2 + 0.044715f * t2 * t2 * t2);
          float e  = __expf(u2);
          float th = 1.0f - 2.0f / (e + 1.0f);
          float gl = 0.5f * t2 * (1.0f + th);
          outh[(size_t)gm * N + gn] = f2bf(gl);
        }
      }
    }
  }
}

// ---------------- 128x64 bf16 NT GEMM, BK=64 2-phase dbuf (proj / MLP2) ----------------
// MODE 1: proj -> xres_bf16 = acc + bias + x_fp32
// MODE 3: mlp2 -> out_fp32 = acc + bias + xres_bf16
template<int MODE>
__global__ __launch_bounds__(256)
void gemm64k(const unsigned short* __restrict__ A, const unsigned short* __restrict__ Bw,
             int K, int N,
             const float* __restrict__ bias, const void* __restrict__ resid,
             float* __restrict__ outf, unsigned short* __restrict__ outh)
{
  __shared__ unsigned short smA[2][128 * 64];   // 16KB each
  __shared__ unsigned short smB[2][64 * 64];    // 8KB each
  const int tid = threadIdx.x;
  const int wv = tid >> 6, ln = tid & 63;
  const int tile_m = blockIdx.x * 128, tile_n = blockIdx.y * 64;
  const int wm = (wv >> 1) * 64, wn = (wv & 1) * 32;

  const int srow8 = ln >> 3;                    // row in 8-row group
  const int sch8  = (ln & 7) ^ srow8;           // pre-swizzled global chunk (of 8)
  const unsigned short* gA = A  + (size_t)(tile_m + wv * 8 + srow8) * K + sch8 * 8;
  const unsigned short* gB = Bw + (size_t)(tile_n + wv * 8 + srow8) * K + sch8 * 8;

  f32x4 acc[4][2] = {};
  const int lr = ln & 15, g = ln >> 4;
  const int rx = lr & 7;                        // read-side row XOR key

  auto stage = [&](int buf, int k0) {
#pragma unroll
    for (int p = 0; p < 4; p++)                 // A: 128 rows
      glds16(gA + (size_t)(p * 32) * K + k0, &smA[buf][(p * 32 + wv * 8) * 64]);
#pragma unroll
    for (int p = 0; p < 2; p++)                 // B: 64 rows
      glds16(gB + (size_t)(p * 32) * K + k0, &smB[buf][(p * 32 + wv * 8) * 64]);
  };

  stage(0, 0);
  __syncthreads();
  int cur = 0;
  for (int k0 = 0; k0 < K; k0 += 64) {
    if (k0 + 64 < K) stage(cur ^ 1, k0 + 64);
    bf16x8 af[4][2], bfr[2][2];
#pragma unroll
    for (int i = 0; i < 4; i++)
#pragma unroll
      for (int c = 0; c < 2; c++)
        af[i][c] = *reinterpret_cast<const bf16x8*>(
            &smA[cur][(wm + i * 16 + lr) * 64 + ((c * 4 + g) ^ rx) * 8]);
#pragma unroll
    for (int j = 0; j < 2; j++)
#pragma unroll
      for (int c = 0; c < 2; c++)
        bfr[j][c] = *reinterpret_cast<const bf16x8*>(
            &smB[cur][(wn + j * 16 + lr) * 64 + ((c * 4 + g) ^ rx) * 8]);
#pragma unroll
    for (int c = 0; c < 2; c++)
#pragma unroll
      for (int i = 0; i < 4; i++)
#pragma unroll
        for (int j = 0; j < 2; j++)
          acc[i][j] = __builtin_amdgcn_mfma_f32_16x16x32_bf16(af[i][c], bfr[j][c], acc[i][j], 0, 0, 0);
    __syncthreads();
    cur ^= 1;
  }

  const int lcol = ln & 15, lrow4 = (ln >> 4) * 4;
#pragma unroll
  for (int i = 0; i < 4; i++) {
#pragma unroll
    for (int j = 0; j < 2; j++) {
      int gm0 = tile_m + wm + i * 16 + lrow4;
      int gn  = tile_n + wn + j * 16 + lcol;
#pragma unroll
      for (int r = 0; r < 4; r++) {
        int gm = gm0 + r;
        float val = acc[i][j][r] + bias[gn];
        if (MODE == 1) {   // + fp32 residual, write bf16 xres
          val += ((const float*)resid)[(size_t)gm * N + gn];
          outh[(size_t)gm * N + gn] = f2bf(val);
        } else {           // + bf16 residual, write fp32 final out
          val += bf2f(((const unsigned short*)resid)[(size_t)gm * N + gn]);
          outf[(size_t)gm * N + gn] = val;
        }
      }
    }
  }
}

// ---------------- flash attention (R5 schedule + setprio; v_perm P-pack, max3 tree) ----------------
__global__ __launch_bounds__(512)
void attn_kernel(const unsigned short* __restrict__ qg, const unsigned short* __restrict__ kg,
                 const unsigned short* __restrict__ vtg, const float* __restrict__ rpb,
                 const int* __restrict__ amask, unsigned short* __restrict__ outh)
{
  constexpr int PSTR = 72;
  __shared__ unsigned short smK[2][64 * 64];
  __shared__ unsigned short smV[2][64 * 64];
  __shared__ unsigned short pls[8][16 * PSTR];
  const int tid = threadIdx.x;
  const int wv = tid >> 6, ln = tid & 63;
  const int bh = blockIdx.x, b = bh >> 4, h = bh & 15;
  const int q0 = blockIdx.y * 128 + wv * 16;
  const unsigned short* qb = qg  + (size_t)bh * SEQ * HD;
  const unsigned short* kb = kg  + (size_t)bh * SEQ * HD;
  const unsigned short* vb = vtg + (size_t)bh * HD * SEQ;
  const int* mp = amask + b * SEQ;
  unsigned short* myp = pls[wv];

  const int lcol = ln & 15, g = ln >> 4, lc8 = g * 8, lrow4 = g * 4;
  const int sw = (lcol & 7) << 3;
  const float* bprow = rpb + (size_t)h * SEQ * SEQ + (size_t)(q0 + lcol) * SEQ;

  const int srr = ln >> 3;
  const int scc = (ln & 7) ^ srr;

  bf16x8 aq0 = *reinterpret_cast<const bf16x8*>(qb + (size_t)(q0 + lcol) * HD + lc8);
  bf16x8 aq1 = *reinterpret_cast<const bf16x8*>(qb + (size_t)(q0 + lcol) * HD + 32 + lc8);

  f32x4 o[4] = {};
  float m = -1e30f, l = 0.f;

  auto stage = [&](int buf, int kt) {
    int row = wv * 8 + srr;
    glds16(kb + (size_t)(kt + row) * HD + scc * 8, &smK[buf][wv * 512]);
    glds16(vb + (size_t)row * SEQ + kt + scc * 8, &smV[buf][wv * 512]);
  };

  stage(0, 0);
  __syncthreads();

  for (int t = 0; t < SEQ / 64; t++) {
    const int cur = t & 1;
    const int kt = t * 64;
    float4 bv4[4]; int4 mv[4];
#pragma unroll
    for (int j = 0; j < 4; j++) {
      bv4[j] = *reinterpret_cast<const float4*>(bprow + kt + j * 16 + lrow4);
      mv[j]  = *reinterpret_cast<const int4*>(mp + kt + j * 16 + lrow4);
    }
    if (t < SEQ / 64 - 1) stage(cur ^ 1, kt + 64);

    f32x4 s[4];
    __builtin_amdgcn_s_setprio(1);
#pragma unroll
    for (int j = 0; j < 4; j++) {
      int r = j * 16 + lcol;
      bf16x8 bk0 = *reinterpret_cast<const bf16x8*>(&smK[cur][r * 64 + (lc8 ^ sw)]);
      bf16x8 bk1 = *reinterpret_cast<const bf16x8*>(&smK[cur][r * 64 + ((32 + lc8) ^ sw)]);
      f32x4 z = {0.f, 0.f, 0.f, 0.f};
      z = __builtin_amdgcn_mfma_f32_16x16x32_bf16(bk0, aq0, z, 0, 0, 0);
      z = __builtin_amdgcn_mfma_f32_16x16x32_bf16(bk1, aq1, z, 0, 0, 0);
      s[j] = z;
    }
    __builtin_amdgcn_s_setprio(0);
#pragma unroll
    for (int j = 0; j < 4; j++) {
      s[j][0] = mv[j].x ? s[j][0] + bv4[j].x : -1e30f;
      s[j][1] = mv[j].y ? s[j][1] + bv4[j].y : -1e30f;
      s[j][2] = mv[j].z ? s[j][2] + bv4[j].z : -1e30f;
      s[j][3] = mv[j].w ? s[j][3] + bv4[j].w : -1e30f;
    }
    float t0 = f3(s[0][0], s[0][1], s[0][2]);
    float t1 = f3(s[0][3], s[1][0], s[1][1]);
    float t2 = f3(s[1][2], s[1][3], s[2][0]);
    float t3 = f3(s[2][1], s[2][2], s[2][3]);
    float t4 = f3(s[3][0], s[3][1], s[3][2]);
    float pm = fmaxf(f3(t0, t1, t2), f3(t3, t4, s[3][3]));
    pm = fmaxf(pm, __shfl_xor(pm, 16));
    pm = fmaxf(pm, __shfl_xor(pm, 32));
    if (m < -1e29f || !__all(pm - m <= 8.0f)) {
      float mn = fmaxf(m, pm);
      float fr = __expf(m - mn);
      m = mn;
      l *= fr;
      float frq[4];
#pragma unroll
      for (int r = 0; r < 4; r++) frq[r] = __shfl(fr, lrow4 + r);
#pragma unroll
      for (int d = 0; d < 4; d++)
#pragma unroll
        for (int r = 0; r < 4; r++) o[d][r] *= frq[r];
    }
    float rs = 0.f;
#pragma unroll
    for (int j = 0; j < 4; j++)
#pragma unroll
      for (int r = 0; r < 4; r++) {
        float p = __expf(s[j][r] - m);
        s[j][r] = p;
        rs += p;
      }
    rs += __shfl_xor(rs, 16);
    rs += __shfl_xor(rs, 32);
    l += rs;
#pragma unroll
    for (int j = 0; j < 4; j++) {
      uint2 pw = { pkbf(s[j][0], s[j][1]), pkbf(s[j][2], s[j][3]) };
      *reinterpret_cast<uint2*>(myp + lcol * PSTR + j * 16 + lrow4) = pw;
    }
    asm volatile("s_waitcnt lgkmcnt(0)" ::: "memory");
    __builtin_amdgcn_sched_barrier(0);
    __builtin_amdgcn_s_setprio(1);
#pragma unroll
    for (int c = 0; c < 2; c++) {
      bf16x8 ap = *reinterpret_cast<const bf16x8*>(myp + lcol * PSTR + c * 32 + lc8);
#pragma unroll
      for (int d = 0; d < 4; d++) {
        int vr = d * 16 + lcol;
        bf16x8 bvv = *reinterpret_cast<const bf16x8*>(&smV[cur][vr * 64 + ((c * 32 + lc8) ^ sw)]);
        o[d] = __builtin_amdgcn_mfma_f32_16x16x32_bf16(ap, bvv, o[d], 0, 0, 0);
      }
    }
    __builtin_amdgcn_s_setprio(0);
    __syncthreads();
  }
  float linv = 1.0f / l;
  float lq[4];
#pragma unroll
  for (int r = 0; r < 4; r++) lq[r] = __shfl(linv, lrow4 + r);
#pragma unroll
  for (int d = 0; d < 4; d++)
#pragma unroll
    for (int r = 0; r < 4; r++)
      outh[(size_t)(b * SEQ + q0 + lrow4 + r) * DIM + h * HD + d * 16 + lcol] = f2bf(o[d][r] * lq[r]);
}

// ---------------- host ----------------
extern "C" void kernel_launch(void* const* d_in, const int* in_sizes, int n_in,
                              void* d_out, int out_size, void* d_ws, size_t ws_size,
                              hipStream_t stream)
{
  const float* x      = (const float*)d_in[0];
  const float* rpb    = (const float*)d_in[1];
  const int*   amask  = (const int*)d_in[2];
  const float* n1w    = (const float*)d_in[3];
  const float* n1b    = (const float*)d_in[4];
  const float* qkv_w  = (const float*)d_in[5];
  const float* q_bias = (const float*)d_in[6];
  const float* v_bias = (const float*)d_in[7];
  const float* proj_w = (const float*)d_in[8];
  const float* proj_b = (const float*)d_in[9];
  const float* n2w    = (const float*)d_in[10];
  const float* n2b    = (const float*)d_in[11];
  const float* w1     = (const float*)d_in[12];
  const float* b1     = (const float*)d_in[13];
  const float* w2     = (const float*)d_in[14];
  const float* b2     = (const float*)d_in[15];
  float* out = (float*)d_out;

  char* ws = (char*)d_ws;
  size_t off = 0;
  auto alloc = [&](size_t bytes) { char* p = ws + off; off += (bytes + 255) & ~(size_t)255; return p; };
  unsigned short* xn1    = (unsigned short*)alloc((size_t)ROWS * DIM * 2);
  unsigned short* xn2    = (unsigned short*)alloc((size_t)ROWS * DIM * 2);
  unsigned short* wqkv_h = (unsigned short*)alloc((size_t)3 * DIM * DIM * 2);
  unsigned short* wproj_h= (unsigned short*)alloc((size_t)DIM * DIM * 2);
  unsigned short* w1_h   = (unsigned short*)alloc((size_t)HIDDEN * DIM * 2);
  unsigned short* w2_h   = (unsigned short*)alloc((size_t)DIM * HIDDEN * 2);
  unsigned short* qh     = (unsigned short*)alloc((size_t)ROWS * DIM * 2);
  unsigned short* kh     = (unsigned short*)alloc((size_t)ROWS * DIM * 2);
  unsigned short* vth    = (unsigned short*)alloc((size_t)ROWS * DIM * 2);
  unsigned short* attn_h = (unsigned short*)alloc((size_t)ROWS * DIM * 2);
  unsigned short* xresh  = (unsigned short*)alloc((size_t)ROWS * DIM * 2);   // bf16 residual
  unsigned short* hmid   = (unsigned short*)alloc((size_t)ROWS * HIDDEN * 2);

  // all weight conversions in one launch
  cvt_all<<<2048, 256, 0, stream>>>(qkv_w, proj_w, w1, w2, wqkv_h, wproj_h, w1_h, w2_h);

  // LN1 (fp32 in)
  ln_kernel<false><<<ROWS, 256, 0, stream>>>(x, n1w, n1b, xn1);
  // QKV GEMM (M=4096, N=3072, K=1024) -- 128x128 BK=64, 768 blocks
  gemm128k<0><<<dim3(ROWS / 128, 3 * DIM / 128), 256, 0, stream>>>(
      xn1, wqkv_h, DIM, 3 * DIM, nullptr, nullptr, qh, kh, vth, q_bias, v_bias);
  // attention -- grid (bh, qblock): XCD = bh%8 -> per-head K/V/rpb locality
  attn_kernel<<<dim3(BATCH * NHEAD, SEQ / 128), 512, 0, stream>>>(qh, kh, vth, rpb, amask, attn_h);
  // proj + residual -> xres (bf16) -- 128x64 BK=64, 512 blocks
  gemm64k<1><<<dim3(ROWS / 128, DIM / 64), 256, 0, stream>>>(
      attn_h, wproj_h, DIM, DIM, proj_b, x, nullptr, xresh);
  // LN2 (bf16 in)
  ln_kernel<true><<<ROWS, 256, 0, stream>>>(xresh, n2w, n2b, xn2);
  // MLP1 + tanh-GELU -- 128x128 BK=64, 1024 blocks
  gemm128k<2><<<dim3(ROWS / 128, HIDDEN / 128), 256, 0, stream>>>(
      xn2, w1_h, DIM, HIDDEN, b1, hmid, nullptr, nullptr, nullptr, nullptr, nullptr);
  // MLP2 + bf16 residual -> out (fp32) -- 128x64 BK=64, 512 blocks
  gemm64k<3><<<dim3(ROWS / 128, DIM / 64), 256, 0, stream>>>(
      hmid, w2_h, HIDDEN, DIM, b2, xresh, out, nullptr);
}

// Round 22
// 252.603 us; speedup vs baseline: 1.0571x; 1.0019x over previous
//
#include <hip/hip_runtime.h>
#include <math.h>

#define DIM 1024
#define NHEAD 16
#define HD 64
#define HIDDEN 4096
#define SEQ 1024
#define BATCH 4
#define ROWS (BATCH*SEQ)   // 4096 tokens

typedef __attribute__((ext_vector_type(8))) short bf16x8;
typedef __attribute__((ext_vector_type(4))) float f32x4;
typedef __attribute__((ext_vector_type(4))) unsigned short us4;

__device__ __forceinline__ unsigned short f2bf(float f) {
  unsigned u = __builtin_bit_cast(unsigned, f);
  u += 0x7fffu + ((u >> 16) & 1u);           // round-to-nearest-even
  return (unsigned short)(u >> 16);
}

__device__ __forceinline__ float bf2f(unsigned short h) {
  unsigned u = (unsigned)h << 16;
  return __builtin_bit_cast(float, u);
}

// pack two f32 -> (bf16(b)<<16)|bf16(a), round-half-up (err <= 2^-9 rel): 2 add + 1 perm
__device__ __forceinline__ unsigned pkbf(float a, float b) {
  unsigned ua = __builtin_bit_cast(unsigned, a) + 0x8000u;
  unsigned ub = __builtin_bit_cast(unsigned, b) + 0x8000u;
  return __builtin_amdgcn_perm(ub, ua, 0x07060302u);  // [ub.b3 ub.b2 ua.b3 ua.b2]
}

__device__ __forceinline__ float f3(float a, float b, float c) {  // fuses to v_max3_f32
  return fmaxf(fmaxf(a, b), c);
}

__device__ __forceinline__ void glds16(const void* g, void* l) {
  __builtin_amdgcn_global_load_lds((const __attribute__((address_space(1))) void*)g,
                                   (__attribute__((address_space(3))) void*)l,
                                   16, 0, 0);
}

// ---------------- fp32 -> bf16 weight conversion (all 4 weights, one launch) ----------------
__global__ void cvt_all(const float* __restrict__ a, const float* __restrict__ b,
                        const float* __restrict__ c, const float* __restrict__ d,
                        unsigned short* __restrict__ oa, unsigned short* __restrict__ ob,
                        unsigned short* __restrict__ oc, unsigned short* __restrict__ od) {
  const int na = 3 * DIM * DIM / 4, nb = DIM * DIM / 4, nc = HIDDEN * DIM / 4, nd = DIM * HIDDEN / 4;
  const int total = na + nb + nc + nd;
  for (int i = blockIdx.x * blockDim.x + threadIdx.x; i < total; i += gridDim.x * blockDim.x) {
    const float* in; unsigned short* out; int j = i;
    if (j < na)             { in = a; out = oa; }
    else if ((j -= na) < nb){ in = b; out = ob; }
    else if ((j -= nb) < nc){ in = c; out = oc; }
    else                    { j -= nc; in = d; out = od; }
    float4 v = reinterpret_cast<const float4*>(in)[j];
    us4 o = { f2bf(v.x), f2bf(v.y), f2bf(v.z), f2bf(v.w) };
    reinterpret_cast<us4*>(out)[j] = o;
  }
}

// ---------------- LayerNorm: fp32 or bf16 row -> bf16 normalized ----------------
template<bool IN_BF16>
__global__ void ln_kernel(const void* __restrict__ xv, const float* __restrict__ w,
                          const float* __restrict__ b, unsigned short* __restrict__ out) {
  int row = blockIdx.x;
  int t = threadIdx.x;
  float4 v;
  if (IN_BF16) {
    const unsigned short* xr = (const unsigned short*)xv + (size_t)row * DIM;
    us4 hv = *reinterpret_cast<const us4*>(xr + t * 4);
    v.x = bf2f(hv[0]); v.y = bf2f(hv[1]); v.z = bf2f(hv[2]); v.w = bf2f(hv[3]);
  } else {
    const float* xr = (const float*)xv + (size_t)row * DIM;
    v = *reinterpret_cast<const float4*>(xr + t * 4);
  }
  float s  = v.x + v.y + v.z + v.w;
  float s2 = v.x*v.x + v.y*v.y + v.z*v.z + v.w*v.w;
#pragma unroll
  for (int m = 1; m < 64; m <<= 1) { s += __shfl_xor(s, m); s2 += __shfl_xor(s2, m); }
  __shared__ float red[8];
  int wv = t >> 6, ln = t & 63;
  if (ln == 0) { red[wv] = s; red[4 + wv] = s2; }
  __syncthreads();
  s  = red[0] + red[1] + red[2] + red[3];
  s2 = red[4] + red[5] + red[6] + red[7];
  float mu  = s * (1.0f / DIM);
  float var = s2 * (1.0f / DIM) - mu * mu;
  float rs  = rsqrtf(var + 1e-5f);
  float4 wv4 = *reinterpret_cast<const float4*>(w + t * 4);
  float4 bv4 = *reinterpret_cast<const float4*>(b + t * 4);
  us4 o = { f2bf((v.x - mu) * rs * wv4.x + bv4.x),
            f2bf((v.y - mu) * rs * wv4.y + bv4.y),
            f2bf((v.z - mu) * rs * wv4.z + bv4.z),
            f2bf((v.w - mu) * rs * wv4.w + bv4.w) };
  *reinterpret_cast<us4*>(out + (size_t)row * DIM + t * 4) = o;
}

// ---------------- 128x128 bf16 NT GEMM, BK=64, 64x64/wave (MLP1 only) ----------------
// Better reads/MFMA ratio (16 b128 per 32 MFMA); grid 1024 = exactly 2 full waves at
// 2 blocks/CU (64KB LDS) -> no tail. QKV must NOT use this (768 blocks -> 512+256 tail).
template<int MODE>
__global__ __launch_bounds__(256)
void gemm128k(const unsigned short* __restrict__ A, const unsigned short* __restrict__ Bw,
              int K, int N,
              const float* __restrict__ bias,
              unsigned short* __restrict__ outh)
{
  __shared__ unsigned short smA[2][128 * 64];   // 16KB each
  __shared__ unsigned short smB[2][128 * 64];   // 16KB each
  const int tid = threadIdx.x;
  const int wv = tid >> 6, ln = tid & 63;
  const int tile_m = blockIdx.x * 128, tile_n = blockIdx.y * 128;
  const int wm = (wv >> 1) * 64, wn = (wv & 1) * 64;

  const int srow8 = ln >> 3;                    // row in 8-row group
  const int sch8  = (ln & 7) ^ srow8;           // pre-swizzled global chunk (of 8)
  const unsigned short* gA = A  + (size_t)(tile_m + wv * 8 + srow8) * K + sch8 * 8;
  const unsigned short* gB = Bw + (size_t)(tile_n + wv * 8 + srow8) * K + sch8 * 8;

  f32x4 acc[4][4] = {};
  const int lr = ln & 15, g = ln >> 4;
  const int rx = lr & 7;                        // read-side row XOR key

  auto stage = [&](int buf, int k0) {
#pragma unroll
    for (int p = 0; p < 4; p++)                 // A: 128 rows
      glds16(gA + (size_t)(p * 32) * K + k0, &smA[buf][(p * 32 + wv * 8) * 64]);
#pragma unroll
    for (int p = 0; p < 4; p++)                 // B: 128 rows
      glds16(gB + (size_t)(p * 32) * K + k0, &smB[buf][(p * 32 + wv * 8) * 64]);
  };

  stage(0, 0);
  __syncthreads();
  int cur = 0;
  for (int k0 = 0; k0 < K; k0 += 64) {
    if (k0 + 64 < K) stage(cur ^ 1, k0 + 64);
    bf16x8 af[4][2], bfr[4][2];
#pragma unroll
    for (int i = 0; i < 4; i++)
#pragma unroll
      for (int c = 0; c < 2; c++)
        af[i][c] = *reinterpret_cast<const bf16x8*>(
            &smA[cur][(wm + i * 16 + lr) * 64 + ((c * 4 + g) ^ rx) * 8]);
#pragma unroll
    for (int j = 0; j < 4; j++)
#pragma unroll
      for (int c = 0; c < 2; c++)
        bfr[j][c] = *reinterpret_cast<const bf16x8*>(
            &smB[cur][(wn + j * 16 + lr) * 64 + ((c * 4 + g) ^ rx) * 8]);
#pragma unroll
    for (int c = 0; c < 2; c++)
#pragma unroll
      for (int i = 0; i < 4; i++)
#pragma unroll
        for (int j = 0; j < 4; j++)
          acc[i][j] = __builtin_amdgcn_mfma_f32_16x16x32_bf16(af[i][c], bfr[j][c], acc[i][j], 0, 0, 0);
    __syncthreads();
    cur ^= 1;
  }

  const int lcol = ln & 15, lrow4 = (ln >> 4) * 4;
#pragma unroll
  for (int i = 0; i < 4; i++) {
#pragma unroll
    for (int j = 0; j < 4; j++) {
      int gm0 = tile_m + wm + i * 16 + lrow4;
      int gn  = tile_n + wn + j * 16 + lcol;
#pragma unroll
      for (int r = 0; r < 4; r++) {
        int gm = gm0 + r;
        float t2 = acc[i][j][r] + bias[gn];
        float u2 = 1.5957691216f * (t2 + 0.044715f * t2 * t2 * t2);
        float e  = __expf(u2);
        float th = 1.0f - 2.0f / (e + 1.0f);
        float gl = 0.5f * t2 * (1.0f + th);
        outh[(size_t)gm * N + gn] = f2bf(gl);
      }
    }
  }
}

// ---------------- 128x64 bf16 NT GEMM, BK=64 2-phase dbuf (QKV / proj / MLP2) ----------------
// MODE 0: QKV -> q (bias+scale), k, vT (bf16); grid 1536 at 3 blocks/CU = 2 full waves.
// MODE 1: proj -> xres_bf16 = acc + bias + x_fp32
// MODE 3: mlp2 -> out_fp32 = acc + bias + xres_bf16
template<int MODE>
__global__ __launch_bounds__(256)
void gemm64k(const unsigned short* __restrict__ A, const unsigned short* __restrict__ Bw,
             int K, int N,
             const float* __restrict__ bias, const void* __restrict__ resid,
             float* __restrict__ outf, unsigned short* __restrict__ outh,
             unsigned short* __restrict__ qo, unsigned short* __restrict__ ko,
             unsigned short* __restrict__ vto,
             const float* __restrict__ qbias, const float* __restrict__ vbias)
{
  __shared__ unsigned short smA[2][128 * 64];   // 16KB each
  __shared__ unsigned short smB[2][64 * 64];    // 8KB each
  const int tid = threadIdx.x;
  const int wv = tid >> 6, ln = tid & 63;
  const int tile_m = blockIdx.x * 128, tile_n = blockIdx.y * 64;
  const int wm = (wv >> 1) * 64, wn = (wv & 1) * 32;

  const int srow8 = ln >> 3;                    // row in 8-row group
  const int sch8  = (ln & 7) ^ srow8;           // pre-swizzled global chunk (of 8)
  const unsigned short* gA = A  + (size_t)(tile_m + wv * 8 + srow8) * K + sch8 * 8;
  const unsigned short* gB = Bw + (size_t)(tile_n + wv * 8 + srow8) * K + sch8 * 8;

  f32x4 acc[4][2] = {};
  const int lr = ln & 15, g = ln >> 4;
  const int rx = lr & 7;                        // read-side row XOR key

  auto stage = [&](int buf, int k0) {
#pragma unroll
    for (int p = 0; p < 4; p++)                 // A: 128 rows
      glds16(gA + (size_t)(p * 32) * K + k0, &smA[buf][(p * 32 + wv * 8) * 64]);
#pragma unroll
    for (int p = 0; p < 2; p++)                 // B: 64 rows
      glds16(gB + (size_t)(p * 32) * K + k0, &smB[buf][(p * 32 + wv * 8) * 64]);
  };

  stage(0, 0);
  __syncthreads();
  int cur = 0;
  for (int k0 = 0; k0 < K; k0 += 64) {
    if (k0 + 64 < K) stage(cur ^ 1, k0 + 64);
    bf16x8 af[4][2], bfr[2][2];
#pragma unroll
    for (int i = 0; i < 4; i++)
#pragma unroll
      for (int c = 0; c < 2; c++)
        af[i][c] = *reinterpret_cast<const bf16x8*>(
            &smA[cur][(wm + i * 16 + lr) * 64 + ((c * 4 + g) ^ rx) * 8]);
#pragma unroll
    for (int j = 0; j < 2; j++)
#pragma unroll
      for (int c = 0; c < 2; c++)
        bfr[j][c] = *reinterpret_cast<const bf16x8*>(
            &smB[cur][(wn + j * 16 + lr) * 64 + ((c * 4 + g) ^ rx) * 8]);
#pragma unroll
    for (int c = 0; c < 2; c++)
#pragma unroll
      for (int i = 0; i < 4; i++)
#pragma unroll
        for (int j = 0; j < 2; j++)
          acc[i][j] = __builtin_amdgcn_mfma_f32_16x16x32_bf16(af[i][c], bfr[j][c], acc[i][j], 0, 0, 0);
    __syncthreads();
    cur ^= 1;
  }

  const int lcol = ln & 15, lrow4 = (ln >> 4) * 4;
#pragma unroll
  for (int i = 0; i < 4; i++) {
#pragma unroll
    for (int j = 0; j < 2; j++) {
      int gm0 = tile_m + wm + i * 16 + lrow4;
      int gn  = tile_n + wn + j * 16 + lcol;
#pragma unroll
      for (int r = 0; r < 4; r++) {
        int gm = gm0 + r;
        float val = acc[i][j][r];
        if (MODE == 0) {
          int b = gm >> 10, n = gm & 1023;
          if (gn < DIM) {
            float q = (val + qbias[gn]) * 0.125f;   // HD^-0.5
            qo[(size_t)((b * NHEAD + (gn >> 6)) * SEQ + n) * HD + (gn & 63)] = f2bf(q);
          } else if (gn < 2 * DIM) {
            int g2 = gn - DIM;
            ko[(size_t)((b * NHEAD + (g2 >> 6)) * SEQ + n) * HD + (g2 & 63)] = f2bf(val);
          } else {
            int g3 = gn - 2 * DIM;
            vto[(size_t)((b * NHEAD + (g3 >> 6)) * HD + (g3 & 63)) * SEQ + n] = f2bf(val + vbias[g3]);
          }
        } else if (MODE == 1) {   // + fp32 residual, write bf16 xres
          val += bias[gn] + ((const float*)resid)[(size_t)gm * N + gn];
          outh[(size_t)gm * N + gn] = f2bf(val);
        } else {                  // + bf16 residual, write fp32 final out
          val += bias[gn] + bf2f(((const unsigned short*)resid)[(size_t)gm * N + gn]);
          outf[(size_t)gm * N + gn] = val;
        }
      }
    }
  }
}

// ---------------- flash attention (R5 schedule + setprio; v_perm P-pack, max3 tree) ----------------
__global__ __launch_bounds__(512)
void attn_kernel(const unsigned short* __restrict__ qg, const unsigned short* __restrict__ kg,
                 const unsigned short* __restrict__ vtg, const float* __restrict__ rpb,
                 const int* __restrict__ amask, unsigned short* __restrict__ outh)
{
  constexpr int PSTR = 72;
  __shared__ unsigned short smK[2][64 * 64];
  __shared__ unsigned short smV[2][64 * 64];
  __shared__ unsigned short pls[8][16 * PSTR];
  const int tid = threadIdx.x;
  const int wv = tid >> 6, ln = tid & 63;
  const int bh = blockIdx.x, b = bh >> 4, h = bh & 15;
  const int q0 = blockIdx.y * 128 + wv * 16;
  const unsigned short* qb = qg  + (size_t)bh * SEQ * HD;
  const unsigned short* kb = kg  + (size_t)bh * SEQ * HD;
  const unsigned short* vb = vtg + (size_t)bh * HD * SEQ;
  const int* mp = amask + b * SEQ;
  unsigned short* myp = pls[wv];

  const int lcol = ln & 15, g = ln >> 4, lc8 = g * 8, lrow4 = g * 4;
  const int sw = (lcol & 7) << 3;
  const float* bprow = rpb + (size_t)h * SEQ * SEQ + (size_t)(q0 + lcol) * SEQ;

  const int srr = ln >> 3;
  const int scc = (ln & 7) ^ srr;

  bf16x8 aq0 = *reinterpret_cast<const bf16x8*>(qb + (size_t)(q0 + lcol) * HD + lc8);
  bf16x8 aq1 = *reinterpret_cast<const bf16x8*>(qb + (size_t)(q0 + lcol) * HD + 32 + lc8);

  f32x4 o[4] = {};
  float m = -1e30f, l = 0.f;

  auto stage = [&](int buf, int kt) {
    int row = wv * 8 + srr;
    glds16(kb + (size_t)(kt + row) * HD + scc * 8, &smK[buf][wv * 512]);
    glds16(vb + (size_t)row * SEQ + kt + scc * 8, &smV[buf][wv * 512]);
  };

  stage(0, 0);
  __syncthreads();

  for (int t = 0; t < SEQ / 64; t++) {
    const int cur = t & 1;
    const int kt = t * 64;
    float4 bv4[4]; int4 mv[4];
#pragma unroll
    for (int j = 0; j < 4; j++) {
      bv4[j] = *reinterpret_cast<const float4*>(bprow + kt + j * 16 + lrow4);
      mv[j]  = *reinterpret_cast<const int4*>(mp + kt + j * 16 + lrow4);
    }
    if (t < SEQ / 64 - 1) stage(cur ^ 1, kt + 64);

    f32x4 s[4];
    __builtin_amdgcn_s_setprio(1);
#pragma unroll
    for (int j = 0; j < 4; j++) {
      int r = j * 16 + lcol;
      bf16x8 bk0 = *reinterpret_cast<const bf16x8*>(&smK[cur][r * 64 + (lc8 ^ sw)]);
      bf16x8 bk1 = *reinterpret_cast<const bf16x8*>(&smK[cur][r * 64 + ((32 + lc8) ^ sw)]);
      f32x4 z = {0.f, 0.f, 0.f, 0.f};
      z = __builtin_amdgcn_mfma_f32_16x16x32_bf16(bk0, aq0, z, 0, 0, 0);
      z = __builtin_amdgcn_mfma_f32_16x16x32_bf16(bk1, aq1, z, 0, 0, 0);
      s[j] = z;
    }
    __builtin_amdgcn_s_setprio(0);
#pragma unroll
    for (int j = 0; j < 4; j++) {
      s[j][0] = mv[j].x ? s[j][0] + bv4[j].x : -1e30f;
      s[j][1] = mv[j].y ? s[j][1] + bv4[j].y : -1e30f;
      s[j][2] = mv[j].z ? s[j][2] + bv4[j].z : -1e30f;
      s[j][3] = mv[j].w ? s[j][3] + bv4[j].w : -1e30f;
    }
    float t0 = f3(s[0][0], s[0][1], s[0][2]);
    float t1 = f3(s[0][3], s[1][0], s[1][1]);
    float t2 = f3(s[1][2], s[1][3], s[2][0]);
    float t3 = f3(s[2][1], s[2][2], s[2][3]);
    float t4 = f3(s[3][0], s[3][1], s[3][2]);
    float pm = fmaxf(f3(t0, t1, t2), f3(t3, t4, s[3][3]));
    pm = fmaxf(pm, __shfl_xor(pm, 16));
    pm = fmaxf(pm, __shfl_xor(pm, 32));
    if (m < -1e29f || !__all(pm - m <= 8.0f)) {
      float mn = fmaxf(m, pm);
      float fr = __expf(m - mn);
      m = mn;
      l *= fr;
      float frq[4];
#pragma unroll
      for (int r = 0; r < 4; r++) frq[r] = __shfl(fr, lrow4 + r);
#pragma unroll
      for (int d = 0; d < 4; d++)
#pragma unroll
        for (int r = 0; r < 4; r++) o[d][r] *= frq[r];
    }
    float rs = 0.f;
#pragma unroll
    for (int j = 0; j < 4; j++)
#pragma unroll
      for (int r = 0; r < 4; r++) {
        float p = __expf(s[j][r] - m);
        s[j][r] = p;
        rs += p;
      }
    rs += __shfl_xor(rs, 16);
    rs += __shfl_xor(rs, 32);
    l += rs;
#pragma unroll
    for (int j = 0; j < 4; j++) {
      uint2 pw = { pkbf(s[j][0], s[j][1]), pkbf(s[j][2], s[j][3]) };
      *reinterpret_cast<uint2*>(myp + lcol * PSTR + j * 16 + lrow4) = pw;
    }
    asm volatile("s_waitcnt lgkmcnt(0)" ::: "memory");
    __builtin_amdgcn_sched_barrier(0);
    __builtin_amdgcn_s_setprio(1);
#pragma unroll
    for (int c = 0; c < 2; c++) {
      bf16x8 ap = *reinterpret_cast<const bf16x8*>(myp + lcol * PSTR + c * 32 + lc8);
#pragma unroll
      for (int d = 0; d < 4; d++) {
        int vr = d * 16 + lcol;
        bf16x8 bvv = *reinterpret_cast<const bf16x8*>(&smV[cur][vr * 64 + ((c * 32 + lc8) ^ sw)]);
        o[d] = __builtin_amdgcn_mfma_f32_16x16x32_bf16(ap, bvv, o[d], 0, 0, 0);
      }
    }
    __builtin_amdgcn_s_setprio(0);
    __syncthreads();
  }
  float linv = 1.0f / l;
  float lq[4];
#pragma unroll
  for (int r = 0; r < 4; r++) lq[r] = __shfl(linv, lrow4 + r);
#pragma unroll
  for (int d = 0; d < 4; d++)
#pragma unroll
    for (int r = 0; r < 4; r++)
      outh[(size_t)(b * SEQ + q0 + lrow4 + r) * DIM + h * HD + d * 16 + lcol] = f2bf(o[d][r] * lq[r]);
}

// ---------------- host ----------------
extern "C" void kernel_launch(void* const* d_in, const int* in_sizes, int n_in,
                              void* d_out, int out_size, void* d_ws, size_t ws_size,
                              hipStream_t stream)
{
  const float* x      = (const float*)d_in[0];
  const float* rpb    = (const float*)d_in[1];
  const int*   amask  = (const int*)d_in[2];
  const float* n1w    = (const float*)d_in[3];
  const float* n1b    = (const float*)d_in[4];
  const float* qkv_w  = (const float*)d_in[5];
  const float* q_bias = (const float*)d_in[6];
  const float* v_bias = (const float*)d_in[7];
  const float* proj_w = (const float*)d_in[8];
  const float* proj_b = (const float*)d_in[9];
  const float* n2w    = (const float*)d_in[10];
  const float* n2b    = (const float*)d_in[11];
  const float* w1     = (const float*)d_in[12];
  const float* b1     = (const float*)d_in[13];
  const float* w2     = (const float*)d_in[14];
  const float* b2     = (const float*)d_in[15];
  float* out = (float*)d_out;

  char* ws = (char*)d_ws;
  size_t off = 0;
  auto alloc = [&](size_t bytes) { char* p = ws + off; off += (bytes + 255) & ~(size_t)255; return p; };
  unsigned short* xn1    = (unsigned short*)alloc((size_t)ROWS * DIM * 2);
  unsigned short* xn2    = (unsigned short*)alloc((size_t)ROWS * DIM * 2);
  unsigned short* wqkv_h = (unsigned short*)alloc((size_t)3 * DIM * DIM * 2);
  unsigned short* wproj_h= (unsigned short*)alloc((size_t)DIM * DIM * 2);
  unsigned short* w1_h   = (unsigned short*)alloc((size_t)HIDDEN * DIM * 2);
  unsigned short* w2_h   = (unsigned short*)alloc((size_t)DIM * HIDDEN * 2);
  unsigned short* qh     = (unsigned short*)alloc((size_t)ROWS * DIM * 2);
  unsigned short* kh     = (unsigned short*)alloc((size_t)ROWS * DIM * 2);
  unsigned short* vth    = (unsigned short*)alloc((size_t)ROWS * DIM * 2);
  unsigned short* attn_h = (unsigned short*)alloc((size_t)ROWS * DIM * 2);
  unsigned short* xresh  = (unsigned short*)alloc((size_t)ROWS * DIM * 2);   // bf16 residual
  unsigned short* hmid   = (unsigned short*)alloc((size_t)ROWS * HIDDEN * 2);

  // all weight conversions in one launch
  cvt_all<<<2048, 256, 0, stream>>>(qkv_w, proj_w, w1, w2, wqkv_h, wproj_h, w1_h, w2_h);

  // LN1 (fp32 in)
  ln_kernel<false><<<ROWS, 256, 0, stream>>>(x, n1w, n1b, xn1);
  // QKV GEMM -- gemm64k BN=64: 1536 blocks at 3 blocks/CU = 2 full waves, no tail
  gemm64k<0><<<dim3(ROWS / 128, 3 * DIM / 64), 256, 0, stream>>>(
      xn1, wqkv_h, DIM, 3 * DIM, nullptr, nullptr, nullptr, nullptr, qh, kh, vth, q_bias, v_bias);
  // attention -- grid (bh, qblock): XCD = bh%8 -> per-head K/V/rpb locality
  attn_kernel<<<dim3(BATCH * NHEAD, SEQ / 128), 512, 0, stream>>>(qh, kh, vth, rpb, amask, attn_h);
  // proj + residual -> xres (bf16) -- gemm64k, 512 blocks
  gemm64k<1><<<dim3(ROWS / 128, DIM / 64), 256, 0, stream>>>(
      attn_h, wproj_h, DIM, DIM, proj_b, x, nullptr, xresh, nullptr, nullptr, nullptr, nullptr, nullptr);
  // LN2 (bf16 in)
  ln_kernel<true><<<ROWS, 256, 0, stream>>>(xresh, n2w, n2b, xn2);
  // MLP1 + tanh-GELU -- gemm128k BN=128: 1024 blocks = 2 full waves at 2 blocks/CU
  gemm128k<2><<<dim3(ROWS / 128, HIDDEN / 128), 256, 0, stream>>>(
      xn2, w1_h, DIM, HIDDEN, b1, hmid);
  // MLP2 + bf16 residual -> out (fp32) -- gemm64k, 512 blocks
  gemm64k<3><<<dim3(ROWS / 128, DIM / 64), 256, 0, stream>>>(
      hmid, w2_h, HIDDEN, DIM, b2, xresh, out, nullptr, nullptr, nullptr, nullptr, nullptr, nullptr);
}